// Round 6
// baseline (413.233 us; speedup 1.0000x reference)
//
#include <hip/hip_runtime.h>

// ---------------- problem constants (match reference setup_inputs) ----------
#define NVOX 12000
#define NPTS 32
#define CIN  5
#define C1   64     // VFE1 out
#define C2   128    // VFE2 out
#define GD   16
#define GH   128
#define GW   128
#define SP   (GD*GH*GW)          // 262144
static constexpr float EPSBN = 1e-5f;

typedef unsigned short ushortT;
typedef __attribute__((ext_vector_type(8))) short bf16x8;
typedef __attribute__((ext_vector_type(4))) float f32x4;

__device__ inline ushortT f2bf(float f) {
    unsigned int x = __float_as_uint(f);
    unsigned int r = (x + 0x7FFFu + ((x >> 16) & 1u)) >> 16;   // RNE
    return (ushortT)r;
}
__device__ inline float bf2f(ushortT u) { return __uint_as_float(((unsigned int)u) << 16); }

// NOTE: biases (b1,b2,cb1..3) are mathematically no-ops: every linear/conv is
// immediately followed by training-mode BN which subtracts the per-channel
// mean; a per-channel constant shifts mean but not variance. Skipped.

// ---------------- prep: weight convert + vfe1 stats + scatter (fused) -------
__global__ void prep(const float* __restrict__ x, const float* __restrict__ w1,
                     float* __restrict__ s1sum,
                     const float* __restrict__ cw1, const float* __restrict__ cw2,
                     const float* __restrict__ cw3, ushortT* __restrict__ wb1,
                     ushortT* __restrict__ wb2, ushortT* __restrict__ wb3,
                     const int* __restrict__ coords, int* __restrict__ winner) {
    __shared__ float s_w[CIN*C1];
    __shared__ float s_red[2][4][C1];
    const int blk = blockIdx.x;
    const int t = threadIdx.x;
    if (blk < 960) {
        for (int i = t; i < CIN*C1; i += 256) s_w[i] = w1[i];
        __syncthreads();
        int ch = t & 63, rr = t >> 6;
        float sum = 0.f, sq = 0.f;
        const int NROWS = NVOX * NPTS;
        for (int row = blk*4 + rr; row < NROWS; row += 960*4) {
            const float* xr = x + row*CIN;
            float y = 0.f;
            #pragma unroll
            for (int c = 0; c < CIN; ++c) y += xr[c] * s_w[c*C1 + ch];
            sum += y; sq += y*y;
        }
        s_red[0][rr][ch] = sum; s_red[1][rr][ch] = sq;
        __syncthreads();
        if (rr == 0) {
            sum = s_red[0][0][ch]+s_red[0][1][ch]+s_red[0][2][ch]+s_red[0][3][ch];
            sq  = s_red[1][0][ch]+s_red[1][1][ch]+s_red[1][2][ch]+s_red[1][3][ch];
            atomicAdd(&s1sum[ch], sum);
            atomicAdd(&s1sum[C1+ch], sq);
        }
    } else if (blk < 1984) {
        // wb[e]: e=(((cig*27+tap)*NCOG+cog)*64+lane)*8+j ; A[row=lane&15][k=(lane>>4)*8+j]
        const int N1 = 4*27*8*512, N2 = 4*27*16*512, N3 = 8*27*16*512;
        const int total = N1+N2+N3;
        for (int e0 = (blk-960)*256 + t; e0 < total; e0 += 1024*256) {
            const float* cw; ushortT* wb; int CI_, NCOG_, e;
            if (e0 < N1)         { cw=cw1; wb=wb1; CI_=128; NCOG_=8;  e=e0; }
            else if (e0 < N1+N2) { cw=cw2; wb=wb2; CI_=128; NCOG_=16; e=e0-N1; }
            else                 { cw=cw3; wb=wb3; CI_=256; NCOG_=16; e=e0-N1-N2; }
            int j = e & 7, lane = (e>>3) & 63, r = e >> 9;
            int cog = r % NCOG_; r /= NCOG_;
            int tap = r % 27;    int cig = r / 27;
            int co = cog*16 + (lane & 15);
            int ci = cig*32 + (lane>>4)*8 + j;
            wb[e] = f2bf(cw[((size_t)co*CI_ + ci)*27 + tap]);
        }
    } else {
        int v = (blk-1984)*256 + t;
        if (v < NVOX) {
            int d = coords[v*3+0], h = coords[v*3+1], w = coords[v*3+2];
            atomicMax(&winner[(d*GH + h)*GW + w], v);
        }
    }
}

// ---------------- VFE1 apply: inline BN finalize ---------------------------
__global__ void vfe1_apply(const float* __restrict__ x, const float* __restrict__ w1,
                           const float* __restrict__ sums, const float* __restrict__ g,
                           const float* __restrict__ be, float* __restrict__ f1) {
    __shared__ float s_w[CIN*C1];
    __shared__ float s_x[NPTS*CIN];
    int v = blockIdx.x, t = threadIdx.x; // 64 threads
    for (int i = t; i < CIN*C1; i += 64) s_w[i] = w1[i];
    for (int i = t; i < NPTS*CIN; i += 64) s_x[i] = x[v*NPTS*CIN + i];
    const float invN = 1.f/(NVOX*NPTS);
    float mean = sums[t]*invN;
    float var  = sums[C1+t]*invN - mean*mean;
    float sc = g[t]*rsqrtf(var + EPSBN);
    float sh = be[t] - mean*sc;
    __syncthreads();
    float m = 0.f;
    for (int p = 0; p < NPTS; ++p) {
        float y = 0.f;
        #pragma unroll
        for (int c = 0; c < CIN; ++c) y += s_x[p*CIN+c]*s_w[c*C1+t];
        m = fmaxf(m, y*sc + sh);
    }
    f1[v*C1 + t] = m;
}

// ---------------- VFE2 linear (transposed padded weights, float4 reads) ----
__global__ void vfe2_linear(const float* __restrict__ f1, const float* __restrict__ w2,
                            float* __restrict__ y2, float* __restrict__ sums) {
    __shared__ float s_w[C2][68];   // [out][in], pad to 68 for bank spread
    __shared__ float s_f[16*C1];
    int t = threadIdx.x; // 128
    for (int i = t; i < C1*C2; i += 128) {
        int c = i >> 7, o = i & 127;
        s_w[o][c] = w2[i];
    }
    int v0 = blockIdx.x*16;
    for (int i = t; i < 16*C1; i += 128) s_f[i] = f1[v0*C1 + i];
    __syncthreads();
    float sum = 0.f, sq = 0.f;
    for (int vl = 0; vl < 16; ++vl) {
        float y = 0.f;
        #pragma unroll
        for (int c4 = 0; c4 < C1; c4 += 4) {
            float4 f = *(const float4*)&s_f[vl*C1 + c4];
            float4 w = *(const float4*)&s_w[t][c4];
            y += f.x*w.x + f.y*w.y + f.z*w.z + f.w*w.w;
        }
        y2[(v0+vl)*C2 + t] = y;
        sum += y; sq += y*y;
    }
    atomicAdd(&sums[t], sum);
    atomicAdd(&sums[C2+t], sq);
}

// VFE2 apply -> bf16, inline finalize
__global__ void vfe2_apply_bf16(const float* __restrict__ y2, const float* __restrict__ sums,
                                const float* __restrict__ g, const float* __restrict__ be,
                                ushortT* __restrict__ f2b) {
    __shared__ float s_sc[C2], s_sh[C2];
    int t = threadIdx.x;
    if (t < C2) {
        const float invN = 1.f/NVOX;
        float mean = sums[t]*invN;
        float var  = sums[C2+t]*invN - mean*mean;
        float sc = g[t]*rsqrtf(var + EPSBN);
        s_sc[t] = sc; s_sh[t] = be[t] - mean*sc;
    }
    __syncthreads();
    int i = blockIdx.x*256 + t;
    if (i >= NVOX*C2/4) return;
    const float4 v = *(const float4*)(y2 + (size_t)i*4);
    int c0 = (i*4) & (C2-1);
    ushort4 o;
    o.x = f2bf(fmaxf(0.f, v.x*s_sc[c0+0]+s_sh[c0+0]));
    o.y = f2bf(fmaxf(0.f, v.y*s_sc[c0+1]+s_sh[c0+1]));
    o.z = f2bf(fmaxf(0.f, v.z*s_sc[c0+2]+s_sh[c0+2]));
    o.w = f2bf(fmaxf(0.f, v.w*s_sc[c0+3]+s_sh[c0+3]));
    *(ushort4*)(f2b + (size_t)i*4) = o;
}

// ---------------- MFMA implicit-GEMM conv3d, stride 2, pad 1, k=3 ----------
// 256 thr = 4 waves (2 co x 2 sp). Block tile CO_T x 64 sp.
// Weights staged per-tap in LDS via depth-2 register pipeline:
//   compute(n) also issues global loads for tap n+2 into regs; after barrier
//   the regs holding tap n+1 are ds_written; barrier; next tap. No memory
//   latency on the critical path; 2 barriers/tap.
template<int CI, int CO, int CO_T, int DI, int HI, int WI, int DO, int HO, int WO,
         int NSLICE, bool GATHER, bool BNSTAGE, bool ATOMIC>
__global__ __launch_bounds__(256, 2) void conv3d_mfma(
        const ushortT* __restrict__ in_cl, const int* __restrict__ winner,
        const ushortT* __restrict__ wb, void* __restrict__ outp,
        float* __restrict__ sums_out,
        const float* __restrict__ bn_sums, const float* __restrict__ bn_g,
        const float* __restrict__ bn_be, float bn_invN) {
    constexpr int NCIG   = CI/32;
    constexpr int NCOG   = CO/16;     // global cog stride per tap in wb
    constexpr int NCOG_T = CO_T/16;   // cogs staged per block
    constexpr int FRAG_M = CO_T/32;
    constexpr int WCH    = CO_T/64;   // int4 weight chunks per thread per tap
    constexpr int CPB    = NCIG/NSLICE;
    __shared__ ushortT s_in[867*40];            // 3*17*17 pos x (32 ci, stride 40)
    __shared__ ushortT s_w[NCOG_T*512];         // one tap's A-fragment tile
    __shared__ short   s_wn[GATHER ? 867 : 2];
    __shared__ float   s_sc[BNSTAGE ? CI : 1];
    __shared__ float   s_sh[BNSTAGE ? CI : 1];

    constexpr int nbx = WO/8, nby = HO/8;
    int b = blockIdx.x;
    const int bx = b % nbx; b /= nbx;
    const int by = b % nby; b /= nby;
    const int bz = b % DO;  b /= DO;
    const int cob   = b % (CO/CO_T);
    const int slice = b / (CO/CO_T);
    const int co0 = cob*CO_T;
    const int oy0 = by*8, ox0 = bx*8;
    const int t = threadIdx.x;
    const int lane = t & 63, wid = t >> 6;
    const int lr = lane & 15, lq = lane >> 4;
    const int wm = wid & 1, wn = wid >> 1;

    if constexpr (BNSTAGE) {
        for (int c = t; c < CI; c += 256) {
            float mean = bn_sums[c]*bn_invN;
            float var  = bn_sums[CI+c]*bn_invN - mean*mean;
            float sc = bn_g[c]*rsqrtf(var + EPSBN);
            s_sc[c] = sc; s_sh[c] = bn_be[c] - mean*sc;
        }
    }
    if constexpr (GATHER) {
        for (int c = t; c < 867; c += 256) {
            int zz = c/289, rr = c - zz*289, yy = rr/17, xx = rr - yy*17;
            int iz = 2*bz-1+zz, iy = 2*oy0-1+yy, ix = 2*ox0-1+xx;
            int wv = -1;
            if ((unsigned)iz < (unsigned)DI && (unsigned)iy < (unsigned)HI &&
                (unsigned)ix < (unsigned)WI)
                wv = winner[(iz*HI + iy)*WI + ix];
            s_wn[c] = (short)wv;
        }
    }

    int bbase[2];
    #pragma unroll
    for (int fn = 0; fn < 2; ++fn) {
        int n = wn*32 + fn*16 + lr;
        int oy = n >> 3, ox = n & 7;
        bbase[fn] = ((2*oy)*17 + 2*ox)*40 + lq*8;
    }

    f32x4 acc[FRAG_M][2];
    #pragma unroll
    for (int i = 0; i < FRAG_M; ++i)
        #pragma unroll
        for (int j = 0; j < 2; ++j) acc[i][j] = (f32x4){0.f,0.f,0.f,0.f};

#define W_ISSUE(dst, tapi) { \
    const ushortT* wt_ = wtile + (size_t)(tapi)*(NCOG*512); \
    _Pragma("unroll") for (int j = 0; j < WCH; ++j) \
        dst[j] = *(const int4*)(wt_ + (t + j*256)*8); }
#define W_WRITE(src) { \
    _Pragma("unroll") for (int j = 0; j < WCH; ++j) \
        *(int4*)(s_w + (t + j*256)*8) = src[j]; }
#define COMPUTE(n) { \
    const int kz_ = (n)/9, ky_ = ((n)/3)%3, kx_ = (n)%3; \
    const int toff_ = (kz_*289 + ky_*17 + kx_)*40; \
    bf16x8 b0 = *(const bf16x8*)(s_in + bbase[0] + toff_); \
    bf16x8 b1 = *(const bf16x8*)(s_in + bbase[1] + toff_); \
    _Pragma("unroll") for (int fm = 0; fm < FRAG_M; ++fm) { \
        bf16x8 a_ = *(const bf16x8*)(s_w + (wm*FRAG_M + fm)*512 + (lane<<3)); \
        acc[fm][0] = __builtin_amdgcn_mfma_f32_16x16x32_bf16(a_, b0, acc[fm][0],0,0,0); \
        acc[fm][1] = __builtin_amdgcn_mfma_f32_16x16x32_bf16(a_, b1, acc[fm][1],0,0,0); } }

    for (int cig = slice*CPB; cig < slice*CPB + CPB; ++cig) {
        __syncthreads();   // all waves done reading s_in / s_w of previous cig
        const ushortT* wtile = wb + ((size_t)(cig*27)*NCOG + (co0 >> 4))*512;
        int4 ra[WCH], rb[WCH];
        W_ISSUE(ra, 0);
        W_ISSUE(rb, 1);
        float scr[8], shr[8];
        if constexpr (BNSTAGE) {
            int ch0 = cig*32 + (t&3)*8;
            #pragma unroll
            for (int j = 0; j < 8; ++j) { scr[j] = s_sc[ch0+j]; shr[j] = s_sh[ch0+j]; }
        }
        // ---- stage input tile (covers ra/rb latency) ----
        for (int c = t; c < 3468; c += 256) {
            int pos = c >> 2, sub = c & 3;
            int4 v = {0,0,0,0};
            if constexpr (GATHER) {
                int w_ = s_wn[pos];
                if (w_ >= 0)
                    v = *(const int4*)(in_cl + (size_t)w_*CI + cig*32 + sub*8);
            } else {
                int zz = pos/289, rr = pos - zz*289, yy = rr/17, xx = rr - yy*17;
                int iz = 2*bz-1+zz, iy = 2*oy0-1+yy, ix = 2*ox0-1+xx;
                if ((unsigned)iz < (unsigned)DI && (unsigned)iy < (unsigned)HI &&
                    (unsigned)ix < (unsigned)WI) {
                    v = *(const int4*)(in_cl + ((size_t)(iz*HI + iy)*WI + ix)*CI
                                             + cig*32 + sub*8);
                    if constexpr (BNSTAGE) {
                        ushortT* u = (ushortT*)&v;
                        #pragma unroll
                        for (int j = 0; j < 8; ++j)
                            u[j] = f2bf(fmaxf(0.f, bf2f(u[j])*scr[j] + shr[j]));
                    }
                }
            }
            *(int4*)(s_in + pos*40 + sub*8) = v;
        }
        W_WRITE(ra);          // tap 0 into s_w (ra long since landed)
        __syncthreads();

        #pragma unroll
        for (int k = 0; k < 13; ++k) {
            COMPUTE(2*k);
            W_ISSUE(ra, (2*k+2 <= 26 ? 2*k+2 : 26));
            __syncthreads();
            W_WRITE(rb);      // tap 2k+1 (loaded one full phase ago)
            __syncthreads();
            COMPUTE(2*k+1);
            W_ISSUE(rb, (2*k+3 <= 26 ? 2*k+3 : 26));
            __syncthreads();
            W_WRITE(ra);      // tap 2k+2
            __syncthreads();
        }
        COMPUTE(26);
    }
#undef W_ISSUE
#undef W_WRITE
#undef COMPUTE

    if constexpr (!ATOMIC) {
        ushortT* out = (ushortT*)outp;
        #pragma unroll
        for (int fm = 0; fm < FRAG_M; ++fm)
        #pragma unroll
        for (int fn = 0; fn < 2; ++fn) {
            int n = wn*32 + fn*16 + lr;
            int oy = n >> 3, ox = n & 7;
            size_t sp = ((size_t)bz*HO + oy0+oy)*WO + ox0+ox;
            int c_ = co0 + wm*(CO_T/2) + fm*16 + lq*4;
            ushort4 o;
            o.x = f2bf(acc[fm][fn][0]); o.y = f2bf(acc[fm][fn][1]);
            o.z = f2bf(acc[fm][fn][2]); o.w = f2bf(acc[fm][fn][3]);
            *(ushort4*)(out + sp*CO + c_) = o;
        }
        // fused BN stats on fp32 accumulators
        #pragma unroll
        for (int fm = 0; fm < FRAG_M; ++fm) {
            float s[4], q[4];
            #pragma unroll
            for (int r = 0; r < 4; ++r) {
                float a0 = acc[fm][0][r], a1 = acc[fm][1][r];
                s[r] = a0 + a1; q[r] = a0*a0 + a1*a1;
                #pragma unroll
                for (int m = 1; m < 16; m <<= 1) {
                    s[r] += __shfl_xor(s[r], m, 64);
                    q[r] += __shfl_xor(q[r], m, 64);
                }
            }
            if (lr == 0) {
                int c_ = co0 + wm*(CO_T/2) + fm*16 + lq*4;
                #pragma unroll
                for (int r = 0; r < 4; ++r) {
                    atomicAdd(&sums_out[c_+r], s[r]);
                    atomicAdd(&sums_out[CO + c_+r], q[r]);
                }
            }
        }
    } else {
        float* out = (float*)outp;
        #pragma unroll
        for (int fm = 0; fm < FRAG_M; ++fm)
        #pragma unroll
        for (int fn = 0; fn < 2; ++fn) {
            int n = wn*32 + fn*16 + lr;
            int oy = n >> 3, ox = n & 7;
            int c_ = co0 + wm*(CO_T/2) + fm*16 + lq*4;
            #pragma unroll
            for (int r = 0; r < 4; ++r)
                atomicAdd(&out[((size_t)(c_+r)*DO + bz)*(HO*WO) + (oy0+oy)*WO + ox0+ox],
                          acc[fm][fn][r]);
        }
    }
}

// ---------------- BN for channel-major fp32 (final output) -----------------
template<int SPL>
__global__ void bn_stats_cmajor(const float* __restrict__ y, const float* __restrict__ g,
                                const float* __restrict__ be, float* __restrict__ ss, int C) {
    __shared__ float s_red[2][256];
    int c = blockIdx.x;
    const float* p = y + (size_t)c*SPL;
    float sum = 0.f, sq = 0.f;
    for (int i = threadIdx.x; i < SPL; i += 256) { float v = p[i]; sum += v; sq += v*v; }
    s_red[0][threadIdx.x] = sum; s_red[1][threadIdx.x] = sq;
    __syncthreads();
    for (int s = 128; s > 0; s >>= 1) {
        if (threadIdx.x < s) {
            s_red[0][threadIdx.x] += s_red[0][threadIdx.x+s];
            s_red[1][threadIdx.x] += s_red[1][threadIdx.x+s];
        }
        __syncthreads();
    }
    if (threadIdx.x == 0) {
        float invN = 1.f/(float)SPL;
        float mean = s_red[0][0]*invN;
        float var  = s_red[1][0]*invN - mean*mean;
        float sc = g[c]*rsqrtf(var + EPSBN);
        ss[c] = sc; ss[C+c] = be[c] - mean*sc;
    }
}

template<int LOGSPL>
__global__ void bn_apply_cmajor(float* __restrict__ y, const float* __restrict__ ss,
                                int C, int total) {
    for (int i = blockIdx.x*blockDim.x + threadIdx.x; i < total; i += gridDim.x*blockDim.x) {
        int c = i >> LOGSPL;
        y[i] = fmaxf(0.f, y[i]*ss[c] + ss[C+c]);
    }
}

// ---------------- host launcher --------------------------------------------
extern "C" void kernel_launch(void* const* d_in, const int* in_sizes, int n_in,
                              void* d_out, int out_size, void* d_ws, size_t ws_size,
                              hipStream_t stream) {
    const float* x      = (const float*)d_in[0];
    const int*   coords = (const int*)  d_in[1];
    const float* w1  = (const float*)d_in[5];
    const float* g1  = (const float*)d_in[7];
    const float* be1 = (const float*)d_in[8];
    const float* w2  = (const float*)d_in[9];
    const float* g2  = (const float*)d_in[11];
    const float* be2 = (const float*)d_in[12];
    const float* cw1 = (const float*)d_in[13];
    const float* cg1 = (const float*)d_in[15];
    const float* cbe1= (const float*)d_in[16];
    const float* cw2 = (const float*)d_in[17];
    const float* cg2 = (const float*)d_in[19];
    const float* cbe2= (const float*)d_in[20];
    const float* cw3 = (const float*)d_in[21];
    const float* cg3 = (const float*)d_in[23];
    const float* cbe3= (const float*)d_in[24];
    float* out = (float*)d_out;

    // ---- workspace layout ----
    float*   ws     = (float*)d_ws;
    float*   stats  = ws;                                   // 4096 f32
    int*     winner = (int*)(ws + 4096);                    // SP
    ushortT* f2b    = (ushortT*)(winner + SP);              // 12000*128
    float*   f1     = (float*)(f2b + (size_t)NVOX*C2);      // 12000*64
    float*   y2     = f1 + (size_t)NVOX*C1;                 // 12000*128
    ushortT* c1o    = (ushortT*)(y2 + (size_t)NVOX*C2);     // 32768*128
    ushortT* c2o    = c1o + (size_t)32768*128;              // 4096*256
    ushortT* wb1    = c2o + (size_t)4096*256;               // 442368
    ushortT* wb2    = wb1 + 442368;                         // 884736
    ushortT* wb3    = wb2 + 884736;                         // 1769472

    float* s1sum = stats;          // 128 (64 sum + 64 sq)
    float* s2sum = stats + 128;    // 256
    float* c1sum = stats + 384;    // 256
    float* c2sum = stats + 640;    // 512
    float* ss3   = stats + 1152;   // 512

    hipMemsetAsync(stats, 0, 4096*sizeof(float), stream);
    hipMemsetAsync(winner, 0xFF, SP*sizeof(int), stream);
    hipMemsetAsync(d_out, 0, (size_t)out_size*sizeof(float), stream);

    // prep: vfe1 stats (960) + weight convert (1024) + scatter (47)
    prep<<<2031, 256, 0, stream>>>(x, w1, s1sum, cw1, cw2, cw3, wb1, wb2, wb3,
                                   coords, winner);

    vfe1_apply<<<NVOX, 64, 0, stream>>>(x, w1, s1sum, g1, be1, f1);
    vfe2_linear<<<NVOX/16, 128, 0, stream>>>(f1, w2, y2, s2sum);
    vfe2_apply_bf16<<<NVOX*C2/4/256, 256, 0, stream>>>(y2, s2sum, g2, be2, f2b);

    // conv1: 128->128, (16,128,128)->(8,64,64); gather via winner, raw bf16 out
    conv3d_mfma<128,128,128, 16,128,128, 8,64,64, 1, true, false, false>
        <<<8*8*8, 256, 0, stream>>>(f2b, winner, wb1, c1o, c1sum,
                                    nullptr, nullptr, nullptr, 0.f);
    // conv2: 128->256, (8,64,64)->(4,32,32); BN1 applied on stage, raw bf16 out
    conv3d_mfma<128,256,64, 8,64,64, 4,32,32, 1, false, true, false>
        <<<4*4*4*4, 256, 0, stream>>>(c1o, nullptr, wb2, c2o, c2sum,
                                      c1sum, cg1, cbe1, 1.f/32768.f);
    // conv3: 256->256, (4,32,32)->(2,16,16); BN2 on stage, split-K x8 atomic out
    conv3d_mfma<256,256,64, 4,32,32, 2,16,16, 8, false, true, true>
        <<<2*2*2*4*8, 256, 0, stream>>>(c2o, nullptr, wb3, (void*)out, nullptr,
                                        c2sum, cg2, cbe2, 1.f/4096.f);

    bn_stats_cmajor<2*16*16><<<256, 256, 0, stream>>>(out, cg3, cbe3, ss3, 256);
    bn_apply_cmajor<9><<<512, 256, 0, stream>>>(out, ss3, 256, 131072);
}

// Round 8
// 407.783 us; speedup vs baseline: 1.0134x; 1.0134x over previous
//
#include <hip/hip_runtime.h>

// ---------------- problem constants (match reference setup_inputs) ----------
#define NVOX 12000
#define NPTS 32
#define CIN  5
#define C1   64     // VFE1 out
#define C2   128    // VFE2 out
#define GD   16
#define GH   128
#define GW   128
#define SP   (GD*GH*GW)          // 262144
static constexpr float EPSBN = 1e-5f;

typedef unsigned short ushortT;
typedef __attribute__((ext_vector_type(8))) short bf16x8;
typedef __attribute__((ext_vector_type(4))) float f32x4;

__device__ inline ushortT f2bf(float f) {
    unsigned int x = __float_as_uint(f);
    unsigned int r = (x + 0x7FFFu + ((x >> 16) & 1u)) >> 16;   // RNE
    return (ushortT)r;
}
__device__ inline float bf2f(ushortT u) { return __uint_as_float(((unsigned int)u) << 16); }

// async global->LDS, 16B per lane; lds base must be wave-uniform
__device__ inline void gload16(const ushortT* g, ushortT* l) {
    __builtin_amdgcn_global_load_lds(
        (const __attribute__((address_space(1))) unsigned int*)g,
        (__attribute__((address_space(3))) unsigned int*)l, 16, 0, 0);
}

// padded spatial dims
#define P1D 18
#define P1H 130
#define P1W 130
#define PSP1 (P1D*P1H*P1W)       // 304200
#define P2D 10
#define P2H 66
#define P2W 66
#define PSP2 (P2D*P2H*P2W)       // 43560
#define P3D 6
#define P3H 34
#define P3W 34
#define PSP3 (P3D*P3H*P3W)       // 6936

// NOTE: biases (b1,b2,cb1..3) are mathematically no-ops: every linear/conv is
// immediately followed by training-mode BN which subtracts the per-channel
// mean; a per-channel constant shifts mean but not variance. Skipped.

// ---------------- prep: weight convert + vfe1 stats + scatter (fused) -------
// wb layout: [cob][cig][tap][cogT][lane][8] (per-block per-cig contiguous)
__device__ inline void conv_w_one(const float* cw, ushortT* wb, int CI_, int CO_T_,
                                  int NCIG_, int e) {
    int NCOG_T_ = CO_T_ >> 4;
    int j = e & 7, lane = (e >> 3) & 63, r = e >> 9;
    int f = r % NCOG_T_; r /= NCOG_T_;
    int tap = r % 27;    r /= 27;
    int cig = r % NCIG_; int cob = r / NCIG_;
    int co = cob*CO_T_ + f*16 + (lane & 15);
    int ci = cig*32 + (lane >> 4)*8 + j;
    wb[e] = f2bf(cw[((size_t)co*CI_ + ci)*27 + tap]);
}

__global__ void prep(const float* __restrict__ x, const float* __restrict__ w1,
                     float* __restrict__ s1sum,
                     const float* __restrict__ cw1, const float* __restrict__ cw2,
                     const float* __restrict__ cw3, ushortT* __restrict__ wb1,
                     ushortT* __restrict__ wb2, ushortT* __restrict__ wb3,
                     const int* __restrict__ coords, int* __restrict__ winner) {
    __shared__ float s_w[CIN*C1];
    __shared__ float s_red[2][4][C1];
    const int blk = blockIdx.x;
    const int t = threadIdx.x;
    if (blk < 960) {
        for (int i = t; i < CIN*C1; i += 256) s_w[i] = w1[i];
        __syncthreads();
        int ch = t & 63, rr = t >> 6;
        float sum = 0.f, sq = 0.f;
        const int NROWS = NVOX * NPTS;
        for (int row = blk*4 + rr; row < NROWS; row += 960*4) {
            const float* xr = x + row*CIN;
            float y = 0.f;
            #pragma unroll
            for (int c = 0; c < CIN; ++c) y += xr[c] * s_w[c*C1 + ch];
            sum += y; sq += y*y;
        }
        s_red[0][rr][ch] = sum; s_red[1][rr][ch] = sq;
        __syncthreads();
        if (rr == 0) {
            sum = s_red[0][0][ch]+s_red[0][1][ch]+s_red[0][2][ch]+s_red[0][3][ch];
            sq  = s_red[1][0][ch]+s_red[1][1][ch]+s_red[1][2][ch]+s_red[1][3][ch];
            atomicAdd(&s1sum[ch], sum);
            atomicAdd(&s1sum[C1+ch], sq);
        }
    } else if (blk < 1984) {
        const int N1 = 442368, N2 = 884736, N3 = 1769472;
        const int total = N1+N2+N3;
        for (int e0 = (blk-960)*256 + t; e0 < total; e0 += 1024*256) {
            if (e0 < N1)         conv_w_one(cw1, wb1, 128, 128, 4, e0);
            else if (e0 < N1+N2) conv_w_one(cw2, wb2, 128, 64,  4, e0-N1);
            else                 conv_w_one(cw3, wb3, 256, 64,  8, e0-N1-N2);
        }
    } else {
        int v = (blk-1984)*256 + t;
        if (v < NVOX) {
            int d = coords[v*3+0], h = coords[v*3+1], w = coords[v*3+2];
            atomicMax(&winner[(d*GH + h)*GW + w], v);
        }
    }
}

// ---------------- VFE1 apply: inline BN finalize ---------------------------
__global__ void vfe1_apply(const float* __restrict__ x, const float* __restrict__ w1,
                           const float* __restrict__ sums, const float* __restrict__ g,
                           const float* __restrict__ be, float* __restrict__ f1) {
    __shared__ float s_w[CIN*C1];
    __shared__ float s_x[NPTS*CIN];
    int v = blockIdx.x, t = threadIdx.x; // 64 threads
    for (int i = t; i < CIN*C1; i += 64) s_w[i] = w1[i];
    for (int i = t; i < NPTS*CIN; i += 64) s_x[i] = x[v*NPTS*CIN + i];
    const float invN = 1.f/(NVOX*NPTS);
    float mean = sums[t]*invN;
    float var  = sums[C1+t]*invN - mean*mean;
    float sc = g[t]*rsqrtf(var + EPSBN);
    float sh = be[t] - mean*sc;
    __syncthreads();
    float m = 0.f;
    for (int p = 0; p < NPTS; ++p) {
        float y = 0.f;
        #pragma unroll
        for (int c = 0; c < CIN; ++c) y += s_x[p*CIN+c]*s_w[c*C1+t];
        m = fmaxf(m, y*sc + sh);
    }
    f1[v*C1 + t] = m;
}

// ---------------- VFE2 linear (transposed padded weights, float4 reads) ----
__global__ void vfe2_linear(const float* __restrict__ f1, const float* __restrict__ w2,
                            float* __restrict__ y2, float* __restrict__ sums) {
    __shared__ float s_w[C2][68];
    __shared__ float s_f[16*C1];
    int t = threadIdx.x; // 128
    for (int i = t; i < C1*C2; i += 128) {
        int c = i >> 7, o = i & 127;
        s_w[o][c] = w2[i];
    }
    int v0 = blockIdx.x*16;
    for (int i = t; i < 16*C1; i += 128) s_f[i] = f1[v0*C1 + i];
    __syncthreads();
    float sum = 0.f, sq = 0.f;
    for (int vl = 0; vl < 16; ++vl) {
        float y = 0.f;
        #pragma unroll
        for (int c4 = 0; c4 < C1; c4 += 4) {
            float4 f = *(const float4*)&s_f[vl*C1 + c4];
            float4 w = *(const float4*)&s_w[t][c4];
            y += f.x*w.x + f.y*w.y + f.z*w.z + f.w*w.w;
        }
        y2[(v0+vl)*C2 + t] = y;
        sum += y; sq += y*y;
    }
    atomicAdd(&sums[t], sum);
    atomicAdd(&sums[C2+t], sq);
}

// VFE2 apply -> bf16, inline finalize
__global__ void vfe2_apply_bf16(const float* __restrict__ y2, const float* __restrict__ sums,
                                const float* __restrict__ g, const float* __restrict__ be,
                                ushortT* __restrict__ f2b) {
    __shared__ float s_sc[C2], s_sh[C2];
    int t = threadIdx.x;
    if (t < C2) {
        const float invN = 1.f/NVOX;
        float mean = sums[t]*invN;
        float var  = sums[C2+t]*invN - mean*mean;
        float sc = g[t]*rsqrtf(var + EPSBN);
        s_sc[t] = sc; s_sh[t] = be[t] - mean*sc;
    }
    __syncthreads();
    int i = blockIdx.x*256 + t;
    if (i >= NVOX*C2/4) return;
    const float4 v = *(const float4*)(y2 + (size_t)i*4);
    int c0 = (i*4) & (C2-1);
    ushort4 o;
    o.x = f2bf(fmaxf(0.f, v.x*s_sc[c0+0]+s_sh[c0+0]));
    o.y = f2bf(fmaxf(0.f, v.y*s_sc[c0+1]+s_sh[c0+1]));
    o.z = f2bf(fmaxf(0.f, v.z*s_sc[c0+2]+s_sh[c0+2]));
    o.w = f2bf(fmaxf(0.f, v.w*s_sc[c0+3]+s_sh[c0+3]));
    *(ushort4*)(f2b + (size_t)i*4) = o;
}

// ---------------- build padded dense grid, cig-major -----------------------
__global__ void build_grid_pad(const int* __restrict__ winner,
                               const ushortT* __restrict__ f2b,
                               ushortT* __restrict__ grid) {
    const int total = 4*PSP1*4;   // cig x pos x 4 chunks
    for (int e = blockIdx.x*256 + threadIdx.x; e < total; e += gridDim.x*256) {
        int sub = e & 3;
        int r = e >> 2;             // cig*PSP1 + pos
        int cig = r / PSP1;
        int pos = r - cig*PSP1;
        int pz = pos / (P1H*P1W);
        int rr = pos - pz*(P1H*P1W);
        int py = rr / P1W;
        int px = rr - py*P1W;
        unsigned dz = pz-1, dy = py-1, dx = px-1;
        int4 v = {0,0,0,0};
        if (dz < GD && dy < GH && dx < GW) {
            int wn = winner[(dz*GH + dy)*GW + dx];
            if (wn >= 0)
                v = *(const int4*)(f2b + (size_t)wn*C2 + cig*32 + sub*8);
        }
        *(int4*)(grid + (size_t)e*8) = v;
    }
}

// ---------------- MFMA implicit-GEMM conv3d, stride 2, k=3 ----------------
// 256 thr = 4 waves (2 co x 2 sp). Block tile CO_T x 64 sp (8x8 per z-slice).
// Inputs: padded cig-major. Weights: per-tap tile streamed via
// global_load_lds, double-buffered, 1 barrier/tap. s_in stride-32, XOR-swizzle.
// BNSTAGE applies BN+relu ONLY to interior positions (pads must stay 0!).
template<int CI, int CO, int CO_T, int PD, int PH, int PW, int DO, int HO, int WO,
         int OPD, int OPH, int OPW, int NSLICE, bool BNSTAGE, bool ATOMIC>
__global__ __launch_bounds__(256, 2) void conv3d_mfma(
        const ushortT* __restrict__ in_p, const ushortT* __restrict__ wb,
        void* __restrict__ outp, float* __restrict__ sums_out,
        const float* __restrict__ bn_sums, const float* __restrict__ bn_g,
        const float* __restrict__ bn_be, float bn_invN) {
    constexpr int NCIG   = CI/32;
    constexpr int NCOG_T = CO_T/16;
    constexpr int FRAG_M = CO_T/32;
    constexpr int WCH    = CO_T/64;       // 16B gload chunks per thread per tap
    constexpr int TAPU   = NCOG_T*512;    // ushorts per tap weight tile
    constexpr int CPB    = NCIG/NSLICE;
    __shared__ ushortT s_in[867*32];      // 3*17*17 pos x 32ci (swizzled)
    __shared__ ushortT s_w[2*TAPU];       // double-buffered tap tile

    constexpr int nbx = WO/8, nby = HO/8;
    int b = blockIdx.x;
    const int bx = b % nbx; b /= nbx;
    const int by = b % nby; b /= nby;
    const int bz = b % DO;  b /= DO;
    const int cob   = b % (CO/CO_T);
    const int slice = b / (CO/CO_T);
    const int co0 = cob*CO_T;
    const int oy0 = by*8, ox0 = bx*8;
    const int t = threadIdx.x;
    const int lane = t & 63, wid = t >> 6;
    const int lr = lane & 15, lq = lane >> 4;
    const int wm = wid & 1, wn = wid >> 1;

    int bb32[2], bq[2];
    #pragma unroll
    for (int fn = 0; fn < 2; ++fn) {
        int n = wn*32 + fn*16 + lr;
        int oy = n >> 3, ox = n & 7;
        int bpos = (2*oy)*17 + 2*ox;
        bb32[fn] = bpos*32;
        bq[fn]   = bpos >> 1;
    }

    f32x4 acc[FRAG_M][2];
    #pragma unroll
    for (int i = 0; i < FRAG_M; ++i)
        #pragma unroll
        for (int j = 0; j < 2; ++j) acc[i][j] = (f32x4){0.f,0.f,0.f,0.f};

#define WLOAD(tapi, bufsel) { \
    const ushortT* ws_ = wsrc + (size_t)(tapi)*TAPU; \
    _Pragma("unroll") for (int j = 0; j < WCH; ++j) \
        gload16(ws_ + (t + j*256)*8, s_w + (bufsel)*TAPU + (wid*64 + j*256)*8); }

#define COMPUTE(n, bufsel) { \
    const int toff_ = ((n)/9)*289 + (((n)/3)%3)*17 + ((n)%3); \
    const int th_ = toff_ >> 1; \
    int cs0 = (((bq[0] + th_) & 3) ^ lq) << 3; \
    int cs1 = (((bq[1] + th_) & 3) ^ lq) << 3; \
    bf16x8 b0 = *(const bf16x8*)(s_in + bb32[0] + toff_*32 + cs0); \
    bf16x8 b1 = *(const bf16x8*)(s_in + bb32[1] + toff_*32 + cs1); \
    const ushortT* wbuf = s_w + (bufsel)*TAPU; \
    _Pragma("unroll") for (int fm = 0; fm < FRAG_M; ++fm) { \
        bf16x8 a_ = *(const bf16x8*)(wbuf + (wm*FRAG_M + fm)*512 + (lane<<3)); \
        acc[fm][0] = __builtin_amdgcn_mfma_f32_16x16x32_bf16(a_, b0, acc[fm][0],0,0,0); \
        acc[fm][1] = __builtin_amdgcn_mfma_f32_16x16x32_bf16(a_, b1, acc[fm][1],0,0,0); } }

    for (int cig = slice*CPB; cig < slice*CPB + CPB; ++cig) {
        const ushortT* wsrc = wb + (((size_t)cob*NCIG + cig)*27)*TAPU;
        WLOAD(0, 0);                       // async: tap0 weights into buf0
        float scr[8], shr[8];
        if constexpr (BNSTAGE) {
            int ch0 = cig*32 + (t&3)*8;
            #pragma unroll
            for (int jj = 0; jj < 8; ++jj) {
                int c = ch0 + jj;
                float mean = bn_sums[c]*bn_invN;
                float var  = bn_sums[CI+c]*bn_invN - mean*mean;
                float sc = bn_g[c]*rsqrtf(var + EPSBN);
                scr[jj] = sc; shr[jj] = bn_be[c] - mean*sc;
            }
        }
        // ---- stage input tile: coalesced reads, swizzled LDS writes ----
        const ushortT* icig = in_p + (size_t)cig*PD*PH*PW*32;
        for (int c = t; c < 3468; c += 256) {
            int pos = c >> 2, sub = c & 3;
            int zz = pos/289, rr = pos - zz*289, yy = rr/17, xx = rr - yy*17;
            int pz = 2*bz + zz, py = 2*oy0 + yy, px = 2*ox0 + xx;
            int4 v = *(const int4*)(icig + ((size_t)(pz*PH + py)*PW + px)*32 + sub*8);
            if constexpr (BNSTAGE) {
                // BN+relu only on interior; pad positions must remain ZERO
                // (stored pads are raw zeros; BN of 0 would be relu(sh) != 0)
                bool inb = ((unsigned)(pz-1) < (unsigned)(PD-2)) &&
                           ((unsigned)(py-1) < (unsigned)(PH-2)) &&
                           ((unsigned)(px-1) < (unsigned)(PW-2));
                if (inb) {
                    ushortT* u = (ushortT*)&v;
                    #pragma unroll
                    for (int jj = 0; jj < 8; ++jj)
                        u[jj] = f2bf(fmaxf(0.f, bf2f(u[jj])*scr[jj] + shr[jj]));
                } else {
                    v = (int4){0,0,0,0};
                }
            }
            int col = sub ^ ((pos >> 1) & 3);
            *(int4*)(s_in + pos*32 + col*8) = v;
        }
        __syncthreads();   // drains WLOAD(0) too

        #pragma unroll
        for (int tap = 0; tap < 27; ++tap) {
            if (tap < 26) WLOAD(tap+1, (tap+1)&1);
            COMPUTE(tap, tap&1);
            __syncthreads();
        }
    }
#undef WLOAD
#undef COMPUTE

    if constexpr (!ATOMIC) {
        // bf16 out in padded cig-major layout for next conv's staging
        ushortT* out = (ushortT*)outp;
        #pragma unroll
        for (int fm = 0; fm < FRAG_M; ++fm)
        #pragma unroll
        for (int fn = 0; fn < 2; ++fn) {
            int n = wn*32 + fn*16 + lr;
            int oy = n >> 3, ox = n & 7;
            int c_ = co0 + wm*(CO_T/2) + fm*16 + lq*4;
            size_t pa = (((size_t)(c_ >> 5)*OPD + bz+1)*OPH + (oy0+oy+1))*OPW + (ox0+ox+1);
            ushort4 o;
            o.x = f2bf(acc[fm][fn][0]); o.y = f2bf(acc[fm][fn][1]);
            o.z = f2bf(acc[fm][fn][2]); o.w = f2bf(acc[fm][fn][3]);
            *(ushort4*)(out + pa*32 + (c_ & 31)) = o;
        }
        // fused BN stats on fp32 accumulators
        #pragma unroll
        for (int fm = 0; fm < FRAG_M; ++fm) {
            float s[4], q[4];
            #pragma unroll
            for (int r = 0; r < 4; ++r) {
                float a0 = acc[fm][0][r], a1 = acc[fm][1][r];
                s[r] = a0 + a1; q[r] = a0*a0 + a1*a1;
                #pragma unroll
                for (int m = 1; m < 16; m <<= 1) {
                    s[r] += __shfl_xor(s[r], m, 64);
                    q[r] += __shfl_xor(q[r], m, 64);
                }
            }
            if (lr == 0) {
                int c_ = co0 + wm*(CO_T/2) + fm*16 + lq*4;
                #pragma unroll
                for (int r = 0; r < 4; ++r) {
                    atomicAdd(&sums_out[c_+r], s[r]);
                    atomicAdd(&sums_out[CO + c_+r], q[r]);
                }
            }
        }
    } else {
        float* out = (float*)outp;
        #pragma unroll
        for (int fm = 0; fm < FRAG_M; ++fm)
        #pragma unroll
        for (int fn = 0; fn < 2; ++fn) {
            int n = wn*32 + fn*16 + lr;
            int oy = n >> 3, ox = n & 7;
            int c_ = co0 + wm*(CO_T/2) + fm*16 + lq*4;
            #pragma unroll
            for (int r = 0; r < 4; ++r)
                atomicAdd(&out[((size_t)(c_+r)*DO + bz)*(HO*WO) + (oy0+oy)*WO + ox0+ox],
                          acc[fm][fn][r]);
        }
    }
}

// ---------------- BN for channel-major fp32 (final output) -----------------
template<int SPL>
__global__ void bn_stats_cmajor(const float* __restrict__ y, const float* __restrict__ g,
                                const float* __restrict__ be, float* __restrict__ ss, int C) {
    __shared__ float s_red[2][256];
    int c = blockIdx.x;
    const float* p = y + (size_t)c*SPL;
    float sum = 0.f, sq = 0.f;
    for (int i = threadIdx.x; i < SPL; i += 256) { float v = p[i]; sum += v; sq += v*v; }
    s_red[0][threadIdx.x] = sum; s_red[1][threadIdx.x] = sq;
    __syncthreads();
    for (int s = 128; s > 0; s >>= 1) {
        if (threadIdx.x < s) {
            s_red[0][threadIdx.x] += s_red[0][threadIdx.x+s];
            s_red[1][threadIdx.x] += s_red[1][threadIdx.x+s];
        }
        __syncthreads();
    }
    if (threadIdx.x == 0) {
        float invN = 1.f/(float)SPL;
        float mean = s_red[0][0]*invN;
        float var  = s_red[1][0]*invN - mean*mean;
        float sc = g[c]*rsqrtf(var + EPSBN);
        ss[c] = sc; ss[C+c] = be[c] - mean*sc;
    }
}

template<int LOGSPL>
__global__ void bn_apply_cmajor(float* __restrict__ y, const float* __restrict__ ss,
                                int C, int total) {
    for (int i = blockIdx.x*blockDim.x + threadIdx.x; i < total; i += gridDim.x*blockDim.x) {
        int c = i >> LOGSPL;
        y[i] = fmaxf(0.f, y[i]*ss[c] + ss[C+c]);
    }
}

// ---------------- host launcher --------------------------------------------
extern "C" void kernel_launch(void* const* d_in, const int* in_sizes, int n_in,
                              void* d_out, int out_size, void* d_ws, size_t ws_size,
                              hipStream_t stream) {
    const float* x      = (const float*)d_in[0];
    const int*   coords = (const int*)  d_in[1];
    const float* w1  = (const float*)d_in[5];
    const float* g1  = (const float*)d_in[7];
    const float* be1 = (const float*)d_in[8];
    const float* w2  = (const float*)d_in[9];
    const float* g2  = (const float*)d_in[11];
    const float* be2 = (const float*)d_in[12];
    const float* cw1 = (const float*)d_in[13];
    const float* cg1 = (const float*)d_in[15];
    const float* cbe1= (const float*)d_in[16];
    const float* cw2 = (const float*)d_in[17];
    const float* cg2 = (const float*)d_in[19];
    const float* cbe2= (const float*)d_in[20];
    const float* cw3 = (const float*)d_in[21];
    const float* cg3 = (const float*)d_in[23];
    const float* cbe3= (const float*)d_in[24];
    float* out = (float*)d_out;

    // ---- workspace layout ----
    float*   ws     = (float*)d_ws;
    float*   stats  = ws;                                    // 4096 f32
    int*     winner = (int*)(ws + 4096);                     // SP ints
    float*   f1     = (float*)(winner + SP);                 // 12000*64 f32
    float*   y2     = f1 + (size_t)NVOX*C1;                  // 12000*128 f32
    ushortT* f2b    = (ushortT*)(y2 + (size_t)NVOX*C2);      // 12000*128 bf16
    ushortT* gridp  = f2b + (size_t)NVOX*C2;                 // 4*PSP1*32
    ushortT* c1o    = gridp + (size_t)4*PSP1*32;             // 4*PSP2*32
    ushortT* c2o    = c1o + (size_t)4*PSP2*32;               // 8*PSP3*32
    ushortT* wb1    = c2o + (size_t)8*PSP3*32;               // 442368
    ushortT* wb2    = wb1 + 442368;                          // 884736
    ushortT* wb3    = wb2 + 884736;                          // 1769472

    float* s1sum = stats;          // 128 (64 sum + 64 sq)
    float* s2sum = stats + 128;    // 256
    float* c1sum = stats + 384;    // 256
    float* c2sum = stats + 640;    // 512
    float* ss3   = stats + 1152;   // 512

    hipMemsetAsync(stats, 0, 4096*sizeof(float), stream);
    hipMemsetAsync(winner, 0xFF, SP*sizeof(int), stream);
    hipMemsetAsync(c1o, 0, (size_t)4*PSP2*32*2, stream);     // zero pads for conv2 stage
    hipMemsetAsync(c2o, 0, (size_t)8*PSP3*32*2, stream);     // zero pads for conv3 stage
    hipMemsetAsync(d_out, 0, (size_t)out_size*sizeof(float), stream);

    // prep: vfe1 stats (960) + weight convert (1024) + scatter (47)
    prep<<<2031, 256, 0, stream>>>(x, w1, s1sum, cw1, cw2, cw3, wb1, wb2, wb3,
                                   coords, winner);

    vfe1_apply<<<NVOX, 64, 0, stream>>>(x, w1, s1sum, g1, be1, f1);
    vfe2_linear<<<NVOX/16, 128, 0, stream>>>(f1, w2, y2, s2sum);
    vfe2_apply_bf16<<<NVOX*C2/4/256, 256, 0, stream>>>(y2, s2sum, g2, be2, f2b);

    // dense padded grid (pads written as zeros; scatter absorbed here)
    build_grid_pad<<<4096, 256, 0, stream>>>(winner, f2b, gridp);

    // conv1: 128->128, grid(18,130,130) -> c1o padded(10,66,66)
    conv3d_mfma<128,128,128, P1D,P1H,P1W, 8,64,64, P2D,P2H,P2W, 1, false, false>
        <<<8*8*8, 256, 0, stream>>>(gridp, wb1, c1o, c1sum,
                                    nullptr, nullptr, nullptr, 0.f);
    // conv2: 128->256, c1o(10,66,66) -> c2o padded(6,34,34); BN1 on stage
    conv3d_mfma<128,256,64, P2D,P2H,P2W, 4,32,32, P3D,P3H,P3W, 1, true, false>
        <<<4*4*4*4, 256, 0, stream>>>(c1o, wb2, c2o, c2sum,
                                      c1sum, cg1, cbe1, 1.f/32768.f);
    // conv3: 256->256, c2o(6,34,34) -> d_out cmajor fp32; BN2 on stage; split-K x8
    conv3d_mfma<256,256,64, P3D,P3H,P3W, 2,16,16, 1,1,1, 8, true, true>
        <<<2*2*2*4*8, 256, 0, stream>>>(c2o, wb3, (void*)out, nullptr,
                                        c2sum, cg2, cbe2, 1.f/4096.f);

    bn_stats_cmajor<2*16*16><<<256, 256, 0, stream>>>(out, cg3, cbe3, ss3, 256);
    bn_apply_cmajor<9><<<512, 256, 0, stream>>>(out, ss3, 256, 131072);
}